// Round 1
// 358.863 us; speedup vs baseline: 1.0923x; 1.0923x over previous
//
#include <hip/hip_runtime.h>

#define N_NODES 50000
#define N_EDGES 1600000
#define N_GRAPHS 256
#define HID 128
#define OUT_CH 10
#define NBUCK 512    // dst buckets for two-phase build
#define BNODES ((N_NODES + NBUCK - 1) / NBUCK)  // 98 nodes per bucket
#define BCAP 6144    // slots per bucket region (mean 3125 + align waste, big headroom)
#define P1BLK 250    // phase-1 blocks (EPB = 6400, divisible by 4)
#define EPB (N_EDGES / P1BLK)
#define DSENTINEL 127  // dloc sentinel for alignment-pad slots (valid dloc < 98)
#define NR 4           // src ranges for L2-windowed gather
#define RSTEP ((N_NODES + NR - 1) / NR)  // 12500 -> 3.2 MB feature window / range
#define PAD_R 40       // slots per (node, range); global max deg <80, per-range max ~30

typedef __bf16 bf16x8 __attribute__((ext_vector_type(8)));
typedef float f32x4 __attribute__((ext_vector_type(4)));

__device__ inline unsigned bf16rne(float f) {
    unsigned u = __float_as_uint(f);
    return (u + 0x7fffu + ((u >> 16) & 1u)) >> 16;
}

// cpair payload: .x = (dloc<<16) | src   (src < 65536, dloc < 98), .y = bitcast w
// ---------------- phase 1: bucket edges, line-aligned per-block reservations -------
__global__ __launch_bounds__(1024) void bucket_k(const int* __restrict__ src,
                                                 const int* __restrict__ dst,
                                                 const float* __restrict__ ew,
                                                 int* __restrict__ bcount,
                                                 int2* __restrict__ cpair) {
    __shared__ int hist[NBUCK];
    __shared__ int base[NBUCK];
    int t = threadIdx.x;
    for (int i = t; i < NBUCK; i += 1024) hist[i] = 0;
    __syncthreads();
    const int ch0 = blockIdx.x * (EPB / 4);
    const int ch1 = ch0 + (EPB / 4);
    const int4* dst4 = (const int4*)dst;
    for (int ci = ch0 + t; ci < ch1; ci += 1024) {
        int4 d4 = dst4[ci];
        atomicAdd(&hist[d4.x / BNODES], 1);
        atomicAdd(&hist[d4.y / BNODES], 1);
        atomicAdd(&hist[d4.z / BNODES], 1);
        atomicAdd(&hist[d4.w / BNODES], 1);
    }
    __syncthreads();
    // reserve line-aligned ranges (8 slots = 64 B): every cpair line owned by ONE block
    for (int i = t; i < NBUCK; i += 1024) {
        int c = hist[i];
        base[i] = (c > 0) ? atomicAdd(&bcount[i], (c + 7) & ~7) : 0;
        hist[i] = 0;  // reuse as within-reservation cursor
    }
    __syncthreads();
    for (int ci = ch0 + t; ci < ch1; ci += 1024) {
        int4 d4 = dst4[ci];
        int e = ci * 4;
#define PROC(dd, ee)                                              \
        {                                                         \
            int b = (dd) / BNODES;                                \
            int off = base[b] + atomicAdd(&hist[b], 1);           \
            if (off < BCAP) {                                     \
                int2 p;                                           \
                p.x = (((dd) - b * BNODES) << 16) | src[ee];      \
                p.y = __float_as_int(ew[ee]);                     \
                cpair[b * BCAP + off] = p;                        \
            }                                                     \
        }
        PROC(d4.x, e)
        PROC(d4.y, e + 1)
        PROC(d4.z, e + 2)
        PROC(d4.w, e + 3)
#undef PROC
    }
    __syncthreads();
    // pad slack slots [c, align8(c)) with sentinel so phase 2 can skip them
    for (int i = t; i < NBUCK; i += 1024) {
        int c = hist[i];
        int ac = (c + 7) & ~7;
        for (int j = c; j < ac; ++j) {
            int off = base[i] + j;
            if (off < BCAP) {
                int2 p;
                p.x = DSENTINEL << 16;
                p.y = 0;
                cpair[i * BCAP + off] = p;
            }
        }
    }
}

// ---------------- phase 2: bucket -> src-range-bucketed ELL + fill4 + dinv ---------
// ELL layout: [n][r][PAD_R] (r = src / RSTEP); fill4[n] = packed uchar4 counts
__global__ __launch_bounds__(512) void ell_scatter_k(const int* __restrict__ bcount,
                                                     const int2* __restrict__ cpair,
                                                     int2* __restrict__ ell,
                                                     unsigned* __restrict__ fill4,
                                                     float* __restrict__ dinv) {
    __shared__ int lfill[BNODES * NR];
    __shared__ float wsum[BNODES];
    int b = blockIdx.x;
    int t = threadIdx.x;
    for (int i = t; i < BNODES * NR; i += 512) lfill[i] = 0;
    for (int i = t; i < BNODES; i += 512) wsum[i] = 0.f;
    __syncthreads();
    int cnt = bcount[b];
    if (cnt > BCAP) cnt = BCAP;
    int n0 = b * BNODES;
    int sbase = b * BCAP;
    for (int i = t; i < cnt; i += 512) {
        int2 p = cpair[sbase + i];
        int dloc = p.x >> 16;
        if (dloc < BNODES) {
            int s = p.x & 0xffff;
            int r = s / RSTEP;
            int pos = atomicAdd(&lfill[dloc * NR + r], 1);
            atomicAdd(&wsum[dloc], __int_as_float(p.y));
            if (pos < PAD_R) {
                int2 q;
                q.x = s;
                q.y = p.y;
                ell[((size_t)(n0 + dloc) * NR + r) * PAD_R + pos] = q;
            }
        }
    }
    __syncthreads();
    for (int i = t; i < BNODES; i += 512) {
        int n = n0 + i;
        if (n < N_NODES) {
            unsigned f = 0;
#pragma unroll
            for (int r = 0; r < NR; ++r) {
                int c = lfill[i * NR + r];
                if (c > PAD_R) c = PAD_R;
                f |= (unsigned)c << (8 * r);
            }
            fill4[n] = f;
            dinv[n] = rsqrtf(wsum[i] + 1.0f);
        }
    }
}

// ---------------- fused prep: graph boundaries + W bf16 transpose ------------------
__global__ __launch_bounds__(256) void prep_k(const int* __restrict__ batch,
                                              int* __restrict__ gstart,
                                              const float* __restrict__ W1,
                                              const float* __restrict__ W2,
                                              const float* __restrict__ W3,
                                              unsigned short* __restrict__ Wt) {
    int idx = blockIdx.x * 256 + threadIdx.x;
    if (idx < 3 * 16384) {
        int m = idx >> 14;
        int r = idx & 16383;
        const float* W = (m == 0) ? W1 : (m == 1) ? W2 : W3;
        int c = r >> 7, k = r & 127;
        Wt[idx] = (unsigned short)bf16rne(W[k * 128 + c]);
    }
    if (idx < N_NODES) {
        int b = batch[idx];
        int bprev = (idx == 0) ? -1 : batch[idx - 1];
        for (int g = bprev + 1; g <= b; ++g) gstart[g] = idx;
        if (idx == N_NODES - 1) {
            for (int g = b + 1; g <= N_GRAPHS; ++g) gstart[g] = N_NODES;
        }
    }
}

// ---------------- one-time x fp32 -> bf16 convert (layer-1 gather table) -----------
__global__ __launch_bounds__(256) void xconv_k(const float* __restrict__ x,
                                               unsigned short* __restrict__ xb) {
    int i = blockIdx.x * 256 + threadIdx.x;  // one thread per 8 channels
    if (i >= N_NODES * 16) return;
    const float4* p = (const float4*)x + (size_t)i * 2;
    float4 lo = p[0], hi = p[1];
    uint4 pk;
    pk.x = bf16rne(lo.x) | (bf16rne(lo.y) << 16);
    pk.y = bf16rne(lo.z) | (bf16rne(lo.w) << 16);
    pk.z = bf16rne(hi.x) | (bf16rne(hi.y) << 16);
    pk.w = bf16rne(hi.z) | (bf16rne(hi.w) << 16);
    ((uint4*)xb)[i] = pk;
}

// ---------------- fused layer: out = relu( agg(x) @ W + b ) ------------------------
// Valid by linearity: agg(x@W) == agg(x)@W (bias/relu applied after aggregation).
// Phase A == previous agg_k geometry (16 nodes/block, 16 lanes/node, 3125 blocks):
// the latency-bound gather keeps its full thread-level parallelism. Phase B is a
// 32-MFMA tail per block (16x128 = tile @ W) that hides under other blocks' stalls.
__global__ __launch_bounds__(256, 6) void aggemm_k(const unsigned short* __restrict__ tb,
                                                   const unsigned* __restrict__ fill4,
                                                   const int2* __restrict__ ell,
                                                   const float* __restrict__ dinv,
                                                   const unsigned short* __restrict__ Wt,
                                                   const float* __restrict__ bias,
                                                   unsigned short* __restrict__ outB,
                                                   int relu) {
    // 272 B row stride (136 shorts): rows shift banks by 4 -> ds_read_b128 hits the
    // 8-phase bank floor (1 KB/instr), no conflict serialization.
    __shared__ unsigned short tile[16][136];
    int lane16 = threadIdx.x & 15;
    int local = threadIdx.x >> 4;
    int n = blockIdx.x * 16 + local;  // 3125*16 == N_NODES exactly, no guard needed
    float dn = dinv[n];
#define UNP(q, f)                                                 \
    float f##0 = __uint_as_float((q).x << 16);                    \
    float f##1 = __uint_as_float((q).x & 0xffff0000u);            \
    float f##2 = __uint_as_float((q).y << 16);                    \
    float f##3 = __uint_as_float((q).y & 0xffff0000u);            \
    float f##4 = __uint_as_float((q).z << 16);                    \
    float f##5 = __uint_as_float((q).z & 0xffff0000u);            \
    float f##6 = __uint_as_float((q).w << 16);                    \
    float f##7 = __uint_as_float((q).w & 0xffff0000u);
    uint4 qs = ((const uint4*)(tb + (size_t)n * 128))[lane16];
    UNP(qs, s)
    float acc0 = s0 * dn, acc1 = s1 * dn, acc2 = s2 * dn, acc3 = s3 * dn;
    float acc4 = s4 * dn, acc5 = s5 * dn, acc6 = s6 * dn, acc7 = s7 * dn;
    unsigned f4 = fill4[n];
#pragma unroll
    for (int r = 0; r < NR; ++r) {
        int c = (f4 >> (8 * r)) & 255;
        const int2* ep = ell + ((size_t)n * NR + r) * PAD_R;
        int i = 0;
        for (; i + 4 <= c; i += 4) {
            int2 p0 = ep[i], p1 = ep[i + 1], p2 = ep[i + 2], p3 = ep[i + 3];
            uint4 q0 = ((const uint4*)(tb + (size_t)p0.x * 128))[lane16];
            uint4 q1 = ((const uint4*)(tb + (size_t)p1.x * 128))[lane16];
            uint4 q2 = ((const uint4*)(tb + (size_t)p2.x * 128))[lane16];
            uint4 q3 = ((const uint4*)(tb + (size_t)p3.x * 128))[lane16];
            float w0 = __int_as_float(p0.y) * dinv[p0.x];
            float w1 = __int_as_float(p1.y) * dinv[p1.x];
            float w2 = __int_as_float(p2.y) * dinv[p2.x];
            float w3 = __int_as_float(p3.y) * dinv[p3.x];
            UNP(q0, a)
            UNP(q1, b)
            UNP(q2, cc)
            UNP(q3, d)
            acc0 += a0 * w0 + b0 * w1 + cc0 * w2 + d0 * w3;
            acc1 += a1 * w0 + b1 * w1 + cc1 * w2 + d1 * w3;
            acc2 += a2 * w0 + b2 * w1 + cc2 * w2 + d2 * w3;
            acc3 += a3 * w0 + b3 * w1 + cc3 * w2 + d3 * w3;
            acc4 += a4 * w0 + b4 * w1 + cc4 * w2 + d4 * w3;
            acc5 += a5 * w0 + b5 * w1 + cc5 * w2 + d5 * w3;
            acc6 += a6 * w0 + b6 * w1 + cc6 * w2 + d6 * w3;
            acc7 += a7 * w0 + b7 * w1 + cc7 * w2 + d7 * w3;
        }
        for (; i < c; ++i) {
            int2 p = ep[i];
            float w = __int_as_float(p.y) * dinv[p.x];
            uint4 q = ((const uint4*)(tb + (size_t)p.x * 128))[lane16];
            UNP(q, a)
            acc0 += a0 * w; acc1 += a1 * w; acc2 += a2 * w; acc3 += a3 * w;
            acc4 += a4 * w; acc5 += a5 * w; acc6 += a6 * w; acc7 += a7 * w;
        }
    }
#undef UNP
    // finish aggregation (out-of-edge dn scale), round to bf16 into the LDS tile
    acc0 *= dn; acc1 *= dn; acc2 *= dn; acc3 *= dn;
    acc4 *= dn; acc5 *= dn; acc6 *= dn; acc7 *= dn;
    uint4 pk;
    pk.x = bf16rne(acc0) | (bf16rne(acc1) << 16);
    pk.y = bf16rne(acc2) | (bf16rne(acc3) << 16);
    pk.z = bf16rne(acc4) | (bf16rne(acc5) << 16);
    pk.w = bf16rne(acc6) | (bf16rne(acc7) << 16);
    *(uint4*)&tile[local][lane16 * 8] = pk;
    __syncthreads();

    // Phase B: C[16][128] = tile @ W; wave w owns output cols [w*32, w*32+32)
    int wave = threadIdx.x >> 6;
    int lane = threadIdx.x & 63;
    int m = lane & 15;     // A row within tile / output col within 16-col tile
    int quad = lane >> 4;  // 0..3 (k-chunk select for A/B frags, row-quad for C)
    f32x4 acc[2] = {};
#pragma unroll
    for (int kc = 0; kc < 4; ++kc) {
        bf16x8 a = *(const bf16x8*)&tile[m][kc * 32 + quad * 8];
#pragma unroll
        for (int ctl = 0; ctl < 2; ++ctl) {
            int ct = wave * 2 + ctl;
            bf16x8 bfr = *(const bf16x8*)(Wt + (size_t)(ct * 16 + m) * 128 + kc * 32 + quad * 8);
            acc[ctl] = __builtin_amdgcn_mfma_f32_16x16x32_bf16(a, bfr, acc[ctl], 0, 0, 0);
        }
    }
#pragma unroll
    for (int ctl = 0; ctl < 2; ++ctl) {
        int col = (wave * 2 + ctl) * 16 + m;
        float bv = bias[col];
#pragma unroll
        for (int r = 0; r < 4; ++r) {
            int nr = blockIdx.x * 16 + quad * 4 + r;
            float v = acc[ctl][r] + bv;
            if (relu) v = fmaxf(v, 0.f);
            outB[(size_t)nr * 128 + col] = (unsigned short)bf16rne(v);
        }
    }
}

// ---------------- pooling stage 1: run-length partial sums over sorted batch -------
#define PCHUNK 49
__global__ __launch_bounds__(128) void pool1_k(const unsigned short* __restrict__ hb,
                                               const int* __restrict__ batch,
                                               float* __restrict__ pool) {
    int c = threadIdx.x;
    int n0 = blockIdx.x * PCHUNK;
    if (n0 >= N_NODES) return;
    int n1 = n0 + PCHUNK;
    if (n1 > N_NODES) n1 = N_NODES;
    int g = batch[n0];
    float run = 0.f;
    for (int n = n0; n < n1; ++n) {
        int gn = batch[n];
        if (gn != g) {
            atomicAdd(&pool[g * 128 + c], run);
            run = 0.f;
            g = gn;
        }
        run += __uint_as_float((unsigned)hb[(size_t)n * 128 + c] << 16);
    }
    atomicAdd(&pool[g * 128 + c], run);
}

// ---------------- classifier: emb = pool/cnt; out = (emb@lw1+lb1)@lw2+lb2 ----------
__global__ __launch_bounds__(128) void cls2_k(const float* __restrict__ pool,
                                              const int* __restrict__ gstart,
                                              const float* __restrict__ lw1,
                                              const float* __restrict__ lb1,
                                              const float* __restrict__ lw2,
                                              const float* __restrict__ lb2,
                                              float* __restrict__ out) {
    __shared__ float emb[128];
    __shared__ float mid[128];
    int g = blockIdx.x, c = threadIdx.x;
    float cntf = fmaxf((float)(gstart[g + 1] - gstart[g]), 1.0f);
    emb[c] = pool[(size_t)g * 128 + c] / cntf;
    __syncthreads();
    float a = lb1[c];
    for (int k = 0; k < 128; ++k) a += emb[k] * lw1[k * 128 + c];
    mid[c] = a;
    __syncthreads();
    if (c < OUT_CH) {
        float o = lb2[c];
        for (int k = 0; k < 128; ++k) o += mid[k] * lw2[k * OUT_CH + c];
        out[g * OUT_CH + c] = o;
    }
}

extern "C" void kernel_launch(void* const* d_in, const int* in_sizes, int n_in,
                              void* d_out, int out_size, void* d_ws, size_t ws_size,
                              hipStream_t stream) {
    const float* x = (const float*)d_in[0];
    const int* ei = (const int*)d_in[1];
    const int* src = ei;
    const int* dst = ei + N_EDGES;
    const float* ew = (const float*)d_in[2];
    const int* batch = (const int*)d_in[3];
    const float* W1 = (const float*)d_in[4];
    const float* b1 = (const float*)d_in[5];
    const float* W2 = (const float*)d_in[6];
    const float* b2 = (const float*)d_in[7];
    const float* W3 = (const float*)d_in[8];
    const float* b3 = (const float*)d_in[9];
    const float* lw1 = (const float*)d_in[10];
    const float* lb1 = (const float*)d_in[11];
    const float* lw2 = (const float*)d_in[12];
    const float* lb2 = (const float*)d_in[13];
    float* out = (float*)d_out;

    char* ws = (char*)d_ws;
    size_t off = 0;
    auto alloc = [&](size_t bytes) {
        size_t cur = off;
        off += (bytes + 255) & ~(size_t)255;
        return cur;
    };
    // zero-init region (one memset): bucket counters + pool sums
    size_t o_bcount = alloc(NBUCK * 4);
    size_t o_pool = alloc(N_GRAPHS * HID * 4);
    size_t zero_end = off;
    // rest
    size_t o_fill4 = alloc(N_NODES * 4);
    size_t o_dinv = alloc(N_NODES * 4);
    size_t o_gstart = alloc((N_GRAPHS + 1) * 4);
    size_t o_wt = alloc(3 * 16384 * 2);
    size_t o_ell = alloc((size_t)N_NODES * NR * PAD_R * 8);
    size_t o_cpair = alloc((size_t)NBUCK * BCAP * 8);
    size_t o_featA = alloc((size_t)N_NODES * HID * 2);  // feature ping (bf16)
    size_t o_featB = alloc((size_t)N_NODES * HID * 2);  // feature pong (bf16)
    (void)ws_size;

    int* bcount = (int*)(ws + o_bcount);
    float* pool = (float*)(ws + o_pool);
    unsigned* fill4 = (unsigned*)(ws + o_fill4);
    float* dinv = (float*)(ws + o_dinv);
    int* gstart = (int*)(ws + o_gstart);
    unsigned short* Wt = (unsigned short*)(ws + o_wt);
    int2* ell = (int2*)(ws + o_ell);
    int2* cpair = (int2*)(ws + o_cpair);
    unsigned short* featA = (unsigned short*)(ws + o_featA);
    unsigned short* featB = (unsigned short*)(ws + o_featB);

    hipMemsetAsync(d_ws, 0, zero_end, stream);

    // two-phase ELL build (line-aligned reservations, src-range-bucketed rows)
    bucket_k<<<P1BLK, 1024, 0, stream>>>(src, dst, ew, bcount, cpair);
    ell_scatter_k<<<NBUCK, 512, 0, stream>>>(bcount, cpair, ell, fill4, dinv);
    prep_k<<<196, 256, 0, stream>>>(batch, gstart, W1, W2, W3, Wt);
    xconv_k<<<(N_NODES * 16 + 255) / 256, 256, 0, stream>>>(x, featA);

    int agg_blocks = (N_NODES + 15) / 16;  // 3125, *16 == N_NODES exactly
    // fused layers: out = relu?( agg(feat) @ W + b )
    aggemm_k<<<agg_blocks, 256, 0, stream>>>(featA, fill4, ell, dinv, Wt, b1, featB, 1);
    aggemm_k<<<agg_blocks, 256, 0, stream>>>(featB, fill4, ell, dinv, Wt + 16384, b2, featA, 1);
    aggemm_k<<<agg_blocks, 256, 0, stream>>>(featA, fill4, ell, dinv, Wt + 32768, b3, featB, 0);

    // two-stage mean-pool (bf16 in) + classify
    pool1_k<<<(N_NODES + PCHUNK - 1) / PCHUNK, 128, 0, stream>>>(featB, batch, pool);
    cls2_k<<<N_GRAPHS, 128, 0, stream>>>(pool, gstart, lw1, lb1, lw2, lb2, out);
}